// Round 2
// baseline (859.784 us; speedup 1.0000x reference)
//
#include <hip/hip_runtime.h>
#include <hip/hip_bf16.h>
#include <math.h>

#define NEG_SLOPE 0.2f

__device__ __forceinline__ float leaky(float x) { return x > 0.f ? x : NEG_SLOPE * x; }

// ---------------- CSR build (dst-indexed) ----------------

__global__ void k_init(int* __restrict__ cnt, int* __restrict__ fill,
                       int* __restrict__ row_ptr, int N, int NT) {
  int i = blockIdx.x * blockDim.x + threadIdx.x;
  if (i < N) { cnt[i] = 1; fill[i] = 0; }  // self-loop pre-counted
  if (i == 0) row_ptr[N] = NT;
}

__global__ void k_hist(const int* __restrict__ ei, int E, int* __restrict__ cnt) {
  int e = blockIdx.x * blockDim.x + threadIdx.x;
  if (e < E) atomicAdd(&cnt[ei[E + e]], 1);  // dst row of edge_index
}

// block partial sums over chunks of 1024
__global__ void k_scanA(const int* __restrict__ cnt, int N, int* __restrict__ bsum) {
  __shared__ int sm[256];
  int base = blockIdx.x * 1024;
  int s = 0;
  for (int j = 0; j < 4; j++) {
    int i = base + threadIdx.x + j * 256;
    if (i < N) s += cnt[i];
  }
  sm[threadIdx.x] = s;
  __syncthreads();
  for (int off = 128; off > 0; off >>= 1) {
    if (threadIdx.x < off) sm[threadIdx.x] += sm[threadIdx.x + off];
    __syncthreads();
  }
  if (threadIdx.x == 0) bsum[blockIdx.x] = sm[0];
}

__global__ void k_scanB(int* __restrict__ bsum, int nb) {
  __shared__ int sm[1024];
  for (int j = threadIdx.x; j < nb; j += blockDim.x) sm[j] = bsum[j];
  __syncthreads();
  if (threadIdx.x == 0) {
    int run = 0;
    for (int j = 0; j < nb; j++) { int t = sm[j]; sm[j] = run; run += t; }
  }
  __syncthreads();
  for (int j = threadIdx.x; j < nb; j += blockDim.x) bsum[j] = sm[j];
}

__global__ void k_scanC(const int* __restrict__ cnt, int N,
                        const int* __restrict__ bsum, int* __restrict__ row_ptr) {
  __shared__ int sm[256];
  int base = blockIdx.x * 1024;
  int loc[4];
  int s = 0;
  for (int j = 0; j < 4; j++) {
    int i = base + threadIdx.x * 4 + j;
    loc[j] = (i < N) ? cnt[i] : 0;
    s += loc[j];
  }
  sm[threadIdx.x] = s;
  __syncthreads();
  // Hillis-Steele inclusive scan over 256 thread sums
  for (int off = 1; off < 256; off <<= 1) {
    int v = sm[threadIdx.x];
    int add = (threadIdx.x >= off) ? sm[threadIdx.x - off] : 0;
    __syncthreads();
    sm[threadIdx.x] = v + add;
    __syncthreads();
  }
  int excl = sm[threadIdx.x] - s;
  int run = bsum[blockIdx.x] + excl;
  for (int j = 0; j < 4; j++) {
    int i = base + threadIdx.x * 4 + j;
    if (i < N) row_ptr[i] = run;
    run += loc[j];
  }
}

__global__ void k_scatter(const int* __restrict__ ei, const float* __restrict__ ew,
                          int E, int N, const int* __restrict__ row_ptr,
                          int* __restrict__ fill, int* __restrict__ csr_src,
                          float* __restrict__ csr_ew) {
  int e = blockIdx.x * blockDim.x + threadIdx.x;
  int NT = E + N;
  if (e >= NT) return;
  int srcn, dstn; float w;
  if (e < E) { srcn = ei[e]; dstn = ei[E + e]; w = ew[e]; }
  else       { srcn = dstn = e - E; w = 1.f; }          // self-loop, weight 1
  int pos = row_ptr[dstn] + atomicAdd(&fill[dstn], 1);
  csr_src[pos] = srcn;
  csr_ew[pos]  = w;
}

// ---------------- GEMM + fused attention scores ----------------
// Computes H[N][64] = X[N][K] @ W[K][Mout] (cols >= Mout zero-padded),
// S[i] = H[i,:]·a_src, D[i] = H[i,:]·a_dst.
// Block: 256 threads, 64-row tile, K staged in 64-chunks via LDS, 4x4 reg tile.
__global__ __launch_bounds__(256)
void k_gemm_score(const float* __restrict__ X, int K,
                  const float* __restrict__ W, int Mout,
                  const float* __restrict__ ASRC, const float* __restrict__ ADST,
                  float* __restrict__ H, float* __restrict__ S, float* __restrict__ D,
                  int N) {
  __shared__ float xs[64][68];  // [k][row], padded: conflict-free b128 reads
  __shared__ float ws[64][68];  // [k][col]
  int tid = threadIdx.x;
  int rg = tid >> 4, cg = tid & 15;
  int rowBase = blockIdx.x * 64;
  float acc[4][4];
#pragma unroll
  for (int i = 0; i < 4; i++)
#pragma unroll
    for (int j = 0; j < 4; j++) acc[i][j] = 0.f;

  int nch = K >> 6;
  for (int kc = 0; kc < nch; kc++) {
    // stage X tile (coalesced float4), transposed into xs[k][row]
#pragma unroll
    for (int j = 0; j < 4; j++) {
      int q = tid + 256 * j;
      int row = q >> 4, kk = (q & 15) << 2;
      int grow = rowBase + row;
      float4 v = make_float4(0.f, 0.f, 0.f, 0.f);
      if (grow < N) v = *(const float4*)&X[(size_t)grow * K + kc * 64 + kk];
      xs[kk + 0][row] = v.x; xs[kk + 1][row] = v.y;
      xs[kk + 2][row] = v.z; xs[kk + 3][row] = v.w;
    }
    // stage W chunk (zero-pad cols >= Mout)
#pragma unroll
    for (int j = 0; j < 4; j++) {
      int q = tid + 256 * j;
      int k = q >> 4, c = (q & 15) << 2;
      int gk = kc * 64 + k;
#pragma unroll
      for (int t = 0; t < 4; t++)
        ws[k][c + t] = (c + t < Mout) ? W[(size_t)gk * Mout + c + t] : 0.f;
    }
    __syncthreads();
#pragma unroll
    for (int k = 0; k < 64; k++) {
      float4 av = *(const float4*)&xs[k][rg << 2];
      float4 bv = *(const float4*)&ws[k][cg << 2];
      acc[0][0] += av.x * bv.x; acc[0][1] += av.x * bv.y;
      acc[0][2] += av.x * bv.z; acc[0][3] += av.x * bv.w;
      acc[1][0] += av.y * bv.x; acc[1][1] += av.y * bv.y;
      acc[1][2] += av.y * bv.z; acc[1][3] += av.y * bv.w;
      acc[2][0] += av.z * bv.x; acc[2][1] += av.z * bv.y;
      acc[2][2] += av.z * bv.z; acc[2][3] += av.z * bv.w;
      acc[3][0] += av.w * bv.x; acc[3][1] += av.w * bv.y;
      acc[3][2] += av.w * bv.z; acc[3][3] += av.w * bv.w;
    }
    __syncthreads();
  }

  // epilogue: store H (stride 64), fused score dot-products
  float as[4], ad[4];
#pragma unroll
  for (int j = 0; j < 4; j++) {
    int c = (cg << 2) + j;
    as[j] = (c < Mout) ? ASRC[c] : 0.f;
    ad[j] = (c < Mout) ? ADST[c] : 0.f;
  }
#pragma unroll
  for (int i = 0; i < 4; i++) {
    int grow = rowBase + (rg << 2) + i;
    if (grow < N) {
      float4 hv = make_float4(acc[i][0], acc[i][1], acc[i][2], acc[i][3]);
      *(float4*)&H[(size_t)grow * 64 + (cg << 2)] = hv;
    }
    float ps = acc[i][0] * as[0] + acc[i][1] * as[1] + acc[i][2] * as[2] + acc[i][3] * as[3];
    float pd = acc[i][0] * ad[0] + acc[i][1] * ad[1] + acc[i][2] * ad[2] + acc[i][3] * ad[3];
#pragma unroll
    for (int off = 1; off < 16; off <<= 1) {
      ps += __shfl_xor(ps, off);
      pd += __shfl_xor(pd, off);
    }
    if (cg == 0 && grow < N) { S[grow] = ps; D[grow] = pd; }
  }
}

// ---------------- per-node softmax stats (max + inverse denom) ----------------
__global__ void k_stats(const int* __restrict__ rp, const int* __restrict__ csr_src,
                        const float* __restrict__ S, const float* __restrict__ D,
                        float* __restrict__ M, float* __restrict__ IDEN, int N) {
  int i = blockIdx.x * blockDim.x + threadIdx.x;
  if (i >= N) return;
  int b = rp[i], e = rp[i + 1];
  float dd = D[i];
  float m = -1e30f;
  for (int t = b; t < e; t++) {
    float sc = leaky(S[csr_src[t]] + dd);
    m = fmaxf(m, sc);
  }
  float den = 0.f;
  for (int t = b; t < e; t++) {
    float sc = leaky(S[csr_src[t]] + dd);
    den += __expf(sc - m);
  }
  M[i] = m;
  IDEN[i] = 1.0f / fmaxf(den, 1e-16f);
}

// ---------------- aggregation: one wave per dst node, lane = feature ----------------
__global__ __launch_bounds__(256)
void k_agg(const int* __restrict__ rp, const int* __restrict__ csr_src,
           const float* __restrict__ csr_ew, const float* __restrict__ S,
           const float* __restrict__ D, const float* __restrict__ M,
           const float* __restrict__ IDEN, const float* __restrict__ Hin,
           float* __restrict__ Out, int F, int ldo, int do_relu, int N) {
  int wid = (blockIdx.x * blockDim.x + threadIdx.x) >> 6;
  int lane = threadIdx.x & 63;
  if (wid >= N) return;
  int b = rp[wid], e = rp[wid + 1];
  float dd = D[wid], mm = M[wid], inv = IDEN[wid];
  float acc = 0.f;
  for (int t = b; t < e; t++) {
    int src = csr_src[t];          // wave-uniform broadcast load
    float w = csr_ew[t];
    float al = __expf(leaky(S[src] + dd) - mm) * inv * w;
    float hv = (lane < F) ? Hin[(size_t)src * 64 + lane] : 0.f;
    acc += hv * al;
  }
  if (lane < F)
    Out[(size_t)wid * ldo + lane] = do_relu ? fmaxf(acc, 0.f) : acc;
}

// ---------------- launch ----------------
extern "C" void kernel_launch(void* const* d_in, const int* in_sizes, int n_in,
                              void* d_out, int out_size, void* d_ws, size_t ws_size,
                              hipStream_t stream) {
  const float* x   = (const float*)d_in[0];
  const int*   ei  = (const int*)d_in[1];
  const float* ew  = (const float*)d_in[2];
  const float* W1  = (const float*)d_in[3];
  const float* a1s = (const float*)d_in[4];
  const float* a1d = (const float*)d_in[5];
  const float* W2  = (const float*)d_in[6];
  const float* a2s = (const float*)d_in[7];
  const float* a2d = (const float*)d_in[8];

  const int HID = in_sizes[4];            // 64
  const int NC  = in_sizes[7];            // 40
  const int FIN = in_sizes[3] / HID;      // 256
  const int N   = in_sizes[0] / FIN;      // 100000
  const int E   = in_sizes[2];            // 1600000
  const int NT  = E + N;
  float* out = (float*)d_out;

  char* wsb = (char*)d_ws;
  size_t off = 0;
  auto alloc = [&](size_t bytes) -> char* {
    char* p = wsb + off;
    off += (bytes + 255) & ~(size_t)255;
    return p;
  };
  float* h1     = (float*)alloc((size_t)N * 64 * 4);
  float* h2     = (float*)alloc((size_t)N * 64 * 4);
  float* S      = (float*)alloc((size_t)N * 4);
  float* D      = (float*)alloc((size_t)N * 4);
  float* M      = (float*)alloc((size_t)N * 4);
  float* IDEN   = (float*)alloc((size_t)N * 4);
  int*   cnt    = (int*)alloc((size_t)N * 4);
  int*   fill   = (int*)alloc((size_t)N * 4);
  int*   rp     = (int*)alloc((size_t)(N + 1) * 4);
  int*   bsum   = (int*)alloc(4096);
  int*   csrsrc = (int*)alloc((size_t)NT * 4);
  float* csrew  = (float*)alloc((size_t)NT * 4);
  (void)ws_size; (void)n_in; (void)out_size;

  const int nb = (N + 1023) / 1024;

  hipLaunchKernelGGL(k_init, dim3((N + 255) / 256), dim3(256), 0, stream, cnt, fill, rp, N, NT);
  hipLaunchKernelGGL(k_hist, dim3((E + 255) / 256), dim3(256), 0, stream, ei, E, cnt);
  hipLaunchKernelGGL(k_scanA, dim3(nb), dim3(256), 0, stream, cnt, N, bsum);
  hipLaunchKernelGGL(k_scanB, dim3(1), dim3(256), 0, stream, bsum, nb);
  hipLaunchKernelGGL(k_scanC, dim3(nb), dim3(256), 0, stream, cnt, N, bsum, rp);
  hipLaunchKernelGGL(k_scatter, dim3((NT + 255) / 256), dim3(256), 0, stream,
                     ei, ew, E, N, rp, fill, csrsrc, csrew);

  const int gblocks = (N + 63) / 64;

  // ---- layer 1: h1 = x@W1, scores; aggregate -> h2 (ReLU) ----
  hipLaunchKernelGGL(k_gemm_score, dim3(gblocks), dim3(256), 0, stream,
                     x, FIN, W1, HID, a1s, a1d, h1, S, D, N);
  hipLaunchKernelGGL(k_stats, dim3((N + 255) / 256), dim3(256), 0, stream,
                     rp, csrsrc, S, D, M, IDEN, N);
  hipLaunchKernelGGL(k_agg, dim3((N + 3) / 4), dim3(256), 0, stream,
                     rp, csrsrc, csrew, S, D, M, IDEN, h1, h2, HID, 64, 1, N);

  // ---- layer 2: g2 = h2@W2 (padded to 64 cols, into h1), scores; aggregate -> out ----
  hipLaunchKernelGGL(k_gemm_score, dim3(gblocks), dim3(256), 0, stream,
                     h2, HID, W2, NC, a2s, a2d, h1, S, D, N);
  hipLaunchKernelGGL(k_stats, dim3((N + 255) / 256), dim3(256), 0, stream,
                     rp, csrsrc, S, D, M, IDEN, N);
  hipLaunchKernelGGL(k_agg, dim3((N + 3) / 4), dim3(256), 0, stream,
                     rp, csrsrc, csrew, S, D, M, IDEN, h1, out, NC, NC, 0, N);
}

// Round 3
// 622.239 us; speedup vs baseline: 1.3818x; 1.3818x over previous
//
#include <hip/hip_runtime.h>
#include <hip/hip_bf16.h>
#include <math.h>

#define NEG_SLOPE 0.2f

__device__ __forceinline__ float leaky(float x) { return x > 0.f ? x : NEG_SLOPE * x; }

// ---------------- CSR build (dst-indexed) ----------------

__global__ void k_init(int* __restrict__ cnt, int* __restrict__ fill,
                       int* __restrict__ row_ptr, int N, int NT) {
  int i = blockIdx.x * blockDim.x + threadIdx.x;
  if (i < N) { cnt[i] = 1; fill[i] = 0; }  // self-loop pre-counted
  if (i == 0) row_ptr[N] = NT;
}

__global__ void k_hist(const int* __restrict__ ei, int E, int* __restrict__ cnt) {
  int e = blockIdx.x * blockDim.x + threadIdx.x;
  if (e < E) atomicAdd(&cnt[ei[E + e]], 1);  // dst row of edge_index
}

// block partial sums over chunks of 1024
__global__ void k_scanA(const int* __restrict__ cnt, int N, int* __restrict__ bsum) {
  __shared__ int sm[256];
  int base = blockIdx.x * 1024;
  int s = 0;
  for (int j = 0; j < 4; j++) {
    int i = base + threadIdx.x + j * 256;
    if (i < N) s += cnt[i];
  }
  sm[threadIdx.x] = s;
  __syncthreads();
  for (int off = 128; off > 0; off >>= 1) {
    if (threadIdx.x < off) sm[threadIdx.x] += sm[threadIdx.x + off];
    __syncthreads();
  }
  if (threadIdx.x == 0) bsum[blockIdx.x] = sm[0];
}

__global__ void k_scanB(int* __restrict__ bsum, int nb) {
  __shared__ int sm[1024];
  for (int j = threadIdx.x; j < nb; j += blockDim.x) sm[j] = bsum[j];
  __syncthreads();
  if (threadIdx.x == 0) {
    int run = 0;
    for (int j = 0; j < nb; j++) { int t = sm[j]; sm[j] = run; run += t; }
  }
  __syncthreads();
  for (int j = threadIdx.x; j < nb; j += blockDim.x) bsum[j] = sm[j];
}

__global__ void k_scanC(const int* __restrict__ cnt, int N,
                        const int* __restrict__ bsum, int* __restrict__ row_ptr) {
  __shared__ int sm[256];
  int base = blockIdx.x * 1024;
  int loc[4];
  int s = 0;
  for (int j = 0; j < 4; j++) {
    int i = base + threadIdx.x * 4 + j;
    loc[j] = (i < N) ? cnt[i] : 0;
    s += loc[j];
  }
  sm[threadIdx.x] = s;
  __syncthreads();
  // Hillis-Steele inclusive scan over 256 thread sums
  for (int off = 1; off < 256; off <<= 1) {
    int v = sm[threadIdx.x];
    int add = (threadIdx.x >= off) ? sm[threadIdx.x - off] : 0;
    __syncthreads();
    sm[threadIdx.x] = v + add;
    __syncthreads();
  }
  int excl = sm[threadIdx.x] - s;
  int run = bsum[blockIdx.x] + excl;
  for (int j = 0; j < 4; j++) {
    int i = base + threadIdx.x * 4 + j;
    if (i < N) row_ptr[i] = run;
    run += loc[j];
  }
}

__global__ void k_scatter(const int* __restrict__ ei, const float* __restrict__ ew,
                          int E, int N, const int* __restrict__ row_ptr,
                          int* __restrict__ fill, int* __restrict__ csr_src,
                          float* __restrict__ csr_ew) {
  int e = blockIdx.x * blockDim.x + threadIdx.x;
  int NT = E + N;
  if (e >= NT) return;
  int srcn, dstn; float w;
  if (e < E) { srcn = ei[e]; dstn = ei[E + e]; w = ew[e]; }
  else       { srcn = dstn = e - E; w = 1.f; }          // self-loop, weight 1
  int pos = row_ptr[dstn] + atomicAdd(&fill[dstn], 1);
  csr_src[pos] = srcn;
  csr_ew[pos]  = w;
}

// ---------------- GEMM + fused attention scores ----------------
// Computes H[N][64] = X[N][K] @ W[K][Mout] (cols >= Mout zero-padded),
// S[i] = H[i,:]·a_src, D[i] = H[i,:]·a_dst.
// Block: 256 threads, 64-row tile, K staged in 64-chunks via LDS, 4x4 reg tile.
__global__ __launch_bounds__(256)
void k_gemm_score(const float* __restrict__ X, int K,
                  const float* __restrict__ W, int Mout,
                  const float* __restrict__ ASRC, const float* __restrict__ ADST,
                  float* __restrict__ H, float* __restrict__ S, float* __restrict__ D,
                  int N) {
  __shared__ float xs[64][68];  // [k][row], padded: conflict-free b128 reads
  __shared__ float ws[64][68];  // [k][col]
  int tid = threadIdx.x;
  int rg = tid >> 4, cg = tid & 15;
  int rowBase = blockIdx.x * 64;
  float acc[4][4];
#pragma unroll
  for (int i = 0; i < 4; i++)
#pragma unroll
    for (int j = 0; j < 4; j++) acc[i][j] = 0.f;

  int nch = K >> 6;
  for (int kc = 0; kc < nch; kc++) {
    // stage X tile (coalesced float4), transposed into xs[k][row]
#pragma unroll
    for (int j = 0; j < 4; j++) {
      int q = tid + 256 * j;
      int row = q >> 4, kk = (q & 15) << 2;
      int grow = rowBase + row;
      float4 v = make_float4(0.f, 0.f, 0.f, 0.f);
      if (grow < N) v = *(const float4*)&X[(size_t)grow * K + kc * 64 + kk];
      xs[kk + 0][row] = v.x; xs[kk + 1][row] = v.y;
      xs[kk + 2][row] = v.z; xs[kk + 3][row] = v.w;
    }
    // stage W chunk (zero-pad cols >= Mout)
#pragma unroll
    for (int j = 0; j < 4; j++) {
      int q = tid + 256 * j;
      int k = q >> 4, c = (q & 15) << 2;
      int gk = kc * 64 + k;
#pragma unroll
      for (int t = 0; t < 4; t++)
        ws[k][c + t] = (c + t < Mout) ? W[(size_t)gk * Mout + c + t] : 0.f;
    }
    __syncthreads();
#pragma unroll
    for (int k = 0; k < 64; k++) {
      float4 av = *(const float4*)&xs[k][rg << 2];
      float4 bv = *(const float4*)&ws[k][cg << 2];
      acc[0][0] += av.x * bv.x; acc[0][1] += av.x * bv.y;
      acc[0][2] += av.x * bv.z; acc[0][3] += av.x * bv.w;
      acc[1][0] += av.y * bv.x; acc[1][1] += av.y * bv.y;
      acc[1][2] += av.y * bv.z; acc[1][3] += av.y * bv.w;
      acc[2][0] += av.z * bv.x; acc[2][1] += av.z * bv.y;
      acc[2][2] += av.z * bv.z; acc[2][3] += av.z * bv.w;
      acc[3][0] += av.w * bv.x; acc[3][1] += av.w * bv.y;
      acc[3][2] += av.w * bv.z; acc[3][3] += av.w * bv.w;
    }
    __syncthreads();
  }

  // epilogue: store H (stride 64), fused score dot-products
  float as[4], ad[4];
#pragma unroll
  for (int j = 0; j < 4; j++) {
    int c = (cg << 2) + j;
    as[j] = (c < Mout) ? ASRC[c] : 0.f;
    ad[j] = (c < Mout) ? ADST[c] : 0.f;
  }
#pragma unroll
  for (int i = 0; i < 4; i++) {
    int grow = rowBase + (rg << 2) + i;
    if (grow < N) {
      float4 hv = make_float4(acc[i][0], acc[i][1], acc[i][2], acc[i][3]);
      *(float4*)&H[(size_t)grow * 64 + (cg << 2)] = hv;
    }
    float ps = acc[i][0] * as[0] + acc[i][1] * as[1] + acc[i][2] * as[2] + acc[i][3] * as[3];
    float pd = acc[i][0] * ad[0] + acc[i][1] * ad[1] + acc[i][2] * ad[2] + acc[i][3] * ad[3];
#pragma unroll
    for (int off = 1; off < 16; off <<= 1) {
      ps += __shfl_xor(ps, off);
      pd += __shfl_xor(pd, off);
    }
    if (cg == 0 && grow < N) { S[grow] = ps; D[grow] = pd; }
  }
}

// ---------------- fused aggregation: online softmax, one wave per dst node ----------------
// Batch-4 edge processing: 4 S-gathers + 4 H-row-gathers in flight per wave.
// Tail is branchless (clamped index, weight 0, score -1e30) — no serial remainder.
__global__ __launch_bounds__(256)
void k_agg_fused(const int* __restrict__ rp, const int* __restrict__ csr_src,
                 const float* __restrict__ csr_ew, const float* __restrict__ S,
                 const float* __restrict__ D, const float* __restrict__ Hin,
                 float* __restrict__ Out, int F, int ldo, int do_relu, int N) {
  int wid = (blockIdx.x * blockDim.x + threadIdx.x) >> 6;
  int lane = threadIdx.x & 63;
  if (wid >= N) return;
  int b = rp[wid], e = rp[wid + 1];
  float dd = D[wid];
  float m = -1e30f, den = 0.f, acc = 0.f;

  for (int t = b; t < e; t += 4) {
    bool v1 = (t + 1 < e), v2 = (t + 2 < e), v3 = (t + 3 < e);
    int t1 = v1 ? t + 1 : t, t2 = v2 ? t + 2 : t, t3 = v3 ? t + 3 : t;
    // level-1 loads: 4 index + 4 weight (wave-uniform broadcast)
    int   i0 = csr_src[t],  i1 = csr_src[t1], i2 = csr_src[t2], i3 = csr_src[t3];
    float w0 = csr_ew[t];
    float w1 = v1 ? csr_ew[t1] : 0.f;
    float w2 = v2 ? csr_ew[t2] : 0.f;
    float w3 = v3 ? csr_ew[t3] : 0.f;
    // level-2 loads: 4 score gathers + 4 feature-row gathers, all independent
    float s0 = S[i0], s1 = S[i1], s2 = S[i2], s3 = S[i3];
    float h0 = Hin[(size_t)i0 * 64 + lane];
    float h1 = Hin[(size_t)i1 * 64 + lane];
    float h2 = Hin[(size_t)i2 * 64 + lane];
    float h3 = Hin[(size_t)i3 * 64 + lane];

    float c0 = leaky(s0 + dd);
    float c1 = v1 ? leaky(s1 + dd) : -1e30f;
    float c2 = v2 ? leaky(s2 + dd) : -1e30f;
    float c3 = v3 ? leaky(s3 + dd) : -1e30f;

    float bm = fmaxf(fmaxf(fmaxf(c0, c1), fmaxf(c2, c3)), m);
    float r = __expf(m - bm);   // wave-uniform rescale (==1 when max unchanged)
    den *= r; acc *= r; m = bm;

    float e0 = __expf(c0 - m), e1 = __expf(c1 - m);
    float e2 = __expf(c2 - m), e3 = __expf(c3 - m);
    den += (e0 + e1) + (e2 + e3);
    acc += h0 * (e0 * w0) + h1 * (e1 * w1) + h2 * (e2 * w2) + h3 * (e3 * w3);
  }

  float o = acc * (1.0f / fmaxf(den, 1e-16f));
  if (lane < F)
    Out[(size_t)wid * ldo + lane] = do_relu ? fmaxf(o, 0.f) : o;
}

// ---------------- launch ----------------
extern "C" void kernel_launch(void* const* d_in, const int* in_sizes, int n_in,
                              void* d_out, int out_size, void* d_ws, size_t ws_size,
                              hipStream_t stream) {
  const float* x   = (const float*)d_in[0];
  const int*   ei  = (const int*)d_in[1];
  const float* ew  = (const float*)d_in[2];
  const float* W1  = (const float*)d_in[3];
  const float* a1s = (const float*)d_in[4];
  const float* a1d = (const float*)d_in[5];
  const float* W2  = (const float*)d_in[6];
  const float* a2s = (const float*)d_in[7];
  const float* a2d = (const float*)d_in[8];

  const int HID = in_sizes[4];            // 64
  const int NC  = in_sizes[7];            // 40
  const int FIN = in_sizes[3] / HID;      // 256
  const int N   = in_sizes[0] / FIN;      // 100000
  const int E   = in_sizes[2];            // 1600000
  const int NT  = E + N;
  float* out = (float*)d_out;

  char* wsb = (char*)d_ws;
  size_t off = 0;
  auto alloc = [&](size_t bytes) -> char* {
    char* p = wsb + off;
    off += (bytes + 255) & ~(size_t)255;
    return p;
  };
  float* h1     = (float*)alloc((size_t)N * 64 * 4);
  float* h2     = (float*)alloc((size_t)N * 64 * 4);
  float* S      = (float*)alloc((size_t)N * 4);
  float* D      = (float*)alloc((size_t)N * 4);
  int*   cnt    = (int*)alloc((size_t)N * 4);
  int*   fill   = (int*)alloc((size_t)N * 4);
  int*   rp     = (int*)alloc((size_t)(N + 1) * 4);
  int*   bsum   = (int*)alloc(4096);
  int*   csrsrc = (int*)alloc((size_t)NT * 4);
  float* csrew  = (float*)alloc((size_t)NT * 4);
  (void)ws_size; (void)n_in; (void)out_size;

  const int nb = (N + 1023) / 1024;

  hipLaunchKernelGGL(k_init, dim3((N + 255) / 256), dim3(256), 0, stream, cnt, fill, rp, N, NT);
  hipLaunchKernelGGL(k_hist, dim3((E + 255) / 256), dim3(256), 0, stream, ei, E, cnt);
  hipLaunchKernelGGL(k_scanA, dim3(nb), dim3(256), 0, stream, cnt, N, bsum);
  hipLaunchKernelGGL(k_scanB, dim3(1), dim3(256), 0, stream, bsum, nb);
  hipLaunchKernelGGL(k_scanC, dim3(nb), dim3(256), 0, stream, cnt, N, bsum, rp);
  hipLaunchKernelGGL(k_scatter, dim3((NT + 255) / 256), dim3(256), 0, stream,
                     ei, ew, E, N, rp, fill, csrsrc, csrew);

  const int gblocks = (N + 63) / 64;

  // ---- layer 1: h1 = x@W1, scores; fused softmax+aggregate -> h2 (ReLU) ----
  hipLaunchKernelGGL(k_gemm_score, dim3(gblocks), dim3(256), 0, stream,
                     x, FIN, W1, HID, a1s, a1d, h1, S, D, N);
  hipLaunchKernelGGL(k_agg_fused, dim3((N + 3) / 4), dim3(256), 0, stream,
                     rp, csrsrc, csrew, S, D, h1, h2, HID, 64, 1, N);

  // ---- layer 2: g2 = h2@W2 (padded to 64 cols, into h1), scores; aggregate -> out ----
  hipLaunchKernelGGL(k_gemm_score, dim3(gblocks), dim3(256), 0, stream,
                     h2, HID, W2, NC, a2s, a2d, h1, S, D, N);
  hipLaunchKernelGGL(k_agg_fused, dim3((N + 3) / 4), dim3(256), 0, stream,
                     rp, csrsrc, csrew, S, D, h1, out, NC, NC, 0, N);
}